// Round 1
// baseline (284.774 us; speedup 1.0000x reference)
//
#include <hip/hip_runtime.h>

// Problem constants (match reference)
constexpr int B = 4;
constexpr int L = 4096;
constexpr int H = 2048;
constexpr int KTAP = 4;
constexpr float EPS = 1e-5f;

constexpr int THREADS = 256;
constexpr int H4 = H / 4;              // 512 float4 groups per row
constexpr int VPT = H4 / THREADS;      // 2 float4 groups per thread

__global__ __launch_bounds__(THREADS)
void fused_conv_res_ln(const float* __restrict__ x,
                       const float* __restrict__ w,      // (H,1,K) -> w[h*4+k]
                       const float* __restrict__ gamma,
                       const float* __restrict__ beta,
                       float* __restrict__ out)
{
    const int row = blockIdx.x;          // 0 .. B*L-1
    const int b   = row / L;
    const int l   = row - b * L;
    const int t   = threadIdx.x;

    const float4* x4  = reinterpret_cast<const float4*>(x) + (size_t)(b) * L * H4;
    const float4* w4  = reinterpret_cast<const float4*>(w);     // w4[c] = 4 taps of channel c
    const float4* g4  = reinterpret_cast<const float4*>(gamma);
    const float4* bt4 = reinterpret_cast<const float4*>(beta);
    float4* o4 = reinterpret_cast<float4*>(out) + (size_t)row * H4;

    float y[VPT][4];
    float sum = 0.f, sumsq = 0.f;

    #pragma unroll
    for (int v = 0; v < VPT; ++v) {
        const int j = t + v * THREADS;   // float4 index within row: 0..511

        // load the 4 conv-window rows (zero-pad for l-3+r < 0)
        float4 xr[KTAP];
        #pragma unroll
        for (int r = 0; r < KTAP; ++r) {
            const int lr = l - (KTAP - 1) + r;
            if (lr >= 0) {
                xr[r] = x4[(size_t)lr * H4 + j];
            } else {
                xr[r] = make_float4(0.f, 0.f, 0.f, 0.f);
            }
        }

        // per-channel weights: channels 4j .. 4j+3, each is one float4 of taps
        const float4 wc0 = w4[4 * j + 0];
        const float4 wc1 = w4[4 * j + 1];
        const float4 wc2 = w4[4 * j + 2];
        const float4 wc3 = w4[4 * j + 3];

        // y = sum_r w[c][r] * x[l-3+r] + x[l]   (residual)
        float y0 = xr[0].x * wc0.x + xr[1].x * wc0.y + xr[2].x * wc0.z + xr[3].x * wc0.w + xr[3].x;
        float y1 = xr[0].y * wc1.x + xr[1].y * wc1.y + xr[2].y * wc1.z + xr[3].y * wc1.w + xr[3].y;
        float y2 = xr[0].z * wc2.x + xr[1].z * wc2.y + xr[2].z * wc2.z + xr[3].z * wc2.w + xr[3].z;
        float y3 = xr[0].w * wc3.x + xr[1].w * wc3.y + xr[2].w * wc3.z + xr[3].w * wc3.w + xr[3].w;

        y[v][0] = y0; y[v][1] = y1; y[v][2] = y2; y[v][3] = y3;

        sum   += y0 + y1 + y2 + y3;
        sumsq += y0 * y0 + y1 * y1 + y2 * y2 + y3 * y3;
    }

    // ---- block reduction: sum, sumsq over 2048 values ----
    #pragma unroll
    for (int off = 32; off > 0; off >>= 1) {
        sum   += __shfl_down(sum,   off, 64);
        sumsq += __shfl_down(sumsq, off, 64);
    }
    __shared__ float s_sum[THREADS / 64];
    __shared__ float s_sq [THREADS / 64];
    const int wave = t >> 6;
    const int lane = t & 63;
    if (lane == 0) { s_sum[wave] = sum; s_sq[wave] = sumsq; }
    __syncthreads();

    float tot = 0.f, totsq = 0.f;
    #pragma unroll
    for (int i = 0; i < THREADS / 64; ++i) { tot += s_sum[i]; totsq += s_sq[i]; }

    const float inv_h = 1.0f / (float)H;
    const float mu    = tot * inv_h;
    const float var   = totsq * inv_h - mu * mu;
    const float rstd  = rsqrtf(var + EPS);

    // ---- normalize + affine + store ----
    #pragma unroll
    for (int v = 0; v < VPT; ++v) {
        const int j = t + v * THREADS;
        const float4 g = g4[j];
        const float4 be = bt4[j];
        float4 o;
        o.x = (y[v][0] - mu) * rstd * g.x + be.x;
        o.y = (y[v][1] - mu) * rstd * g.y + be.y;
        o.z = (y[v][2] - mu) * rstd * g.z + be.z;
        o.w = (y[v][3] - mu) * rstd * g.w + be.w;
        o4[j] = o;
    }
}

extern "C" void kernel_launch(void* const* d_in, const int* in_sizes, int n_in,
                              void* d_out, int out_size, void* d_ws, size_t ws_size,
                              hipStream_t stream) {
    const float* x     = (const float*)d_in[0];
    const float* w     = (const float*)d_in[1];
    const float* gamma = (const float*)d_in[2];
    const float* beta  = (const float*)d_in[3];
    float* out = (float*)d_out;

    dim3 grid(B * L);
    dim3 block(THREADS);
    fused_conv_res_ln<<<grid, block, 0, stream>>>(x, w, gamma, beta, out);
}

// Round 2
// 249.003 us; speedup vs baseline: 1.1437x; 1.1437x over previous
//
#include <hip/hip_runtime.h>

// Problem constants (match reference)
constexpr int B = 4;
constexpr int L = 4096;
constexpr int H = 2048;
constexpr int KTAP = 4;
constexpr float EPS = 1e-5f;

constexpr int THREADS = 256;
constexpr int H4 = H / 4;              // 512 float4 groups per row
constexpr int COLS = H4 / THREADS;     // 2 float4 groups per thread
constexpr int ROWS = 8;                // rows (l values) per block
constexpr int TILES = (B * L) / ROWS;  // 2048 blocks
constexpr int TPB = L / ROWS;          // 512 tiles per batch
constexpr int NXCD = 8;
constexpr int WAVES = THREADS / 64;

__global__ __launch_bounds__(THREADS)
void fused_conv_res_ln(const float4* __restrict__ x4,
                       const float4* __restrict__ w4,    // w4[c] = 4 taps of channel c
                       const float4* __restrict__ g4,
                       const float4* __restrict__ bt4,
                       float4* __restrict__ o4)
{
    // Bijective XCD-chunked swizzle: consecutive logical tiles land on the
    // same XCD so the 3-row halo between adjacent tiles is L2-local.
    // TILES (2048) is divisible by NXCD (8).
    const int bid     = blockIdx.x;
    const int logical = (bid & (NXCD - 1)) * (TILES / NXCD) + (bid >> 3);
    const int b       = logical / TPB;
    const int tile    = logical - b * TPB;
    const int l0      = tile * ROWS;
    const int t       = threadIdx.x;

    const size_t rowbase = (size_t)b * L;   // row index offset for this batch

    // Per-column persistent state (loaded once per block)
    float4 xw[COLS][KTAP];   // sliding window of input rows
    float4 wc[COLS][4];      // per-channel taps (channel = 4j+comp)
    float4 gg[COLS], bb[COLS];
    int    jj[COLS];

    #pragma unroll
    for (int c = 0; c < COLS; ++c) {
        const int j = t + c * THREADS;
        jj[c] = j;
        #pragma unroll
        for (int k = 0; k < 4; ++k) wc[c][k] = w4[4 * j + k];
        gg[c] = g4[j];
        bb[c] = bt4[j];
        // window init: rows l0-3 .. l0-1 (zero-padded per batch), plus row l0
        #pragma unroll
        for (int k = 0; k < 3; ++k) {
            const int lr = l0 - 3 + k;
            xw[c][k] = (lr >= 0) ? x4[(rowbase + lr) * H4 + j]
                                 : make_float4(0.f, 0.f, 0.f, 0.f);
        }
        xw[c][3] = x4[(rowbase + l0) * H4 + j];
    }

    __shared__ float s_sum[ROWS][WAVES];
    __shared__ float s_sq [ROWS][WAVES];
    const int wave = t >> 6;
    const int lane = t & 63;

    #pragma unroll
    for (int r = 0; r < ROWS; ++r) {
        // ---- prefetch next row BEFORE the reduction (hide HBM latency) ----
        float4 xn[COLS];
        if (r + 1 < ROWS) {
            #pragma unroll
            for (int c = 0; c < COLS; ++c)
                xn[c] = x4[(rowbase + l0 + r + 1) * H4 + jj[c]];
        }

        // ---- conv + residual ----
        float y[COLS][4];
        float sum = 0.f, sq = 0.f;
        #pragma unroll
        for (int c = 0; c < COLS; ++c) {
            const float4 a0 = xw[c][0], a1 = xw[c][1], a2 = xw[c][2], a3 = xw[c][3];
            y[c][0] = a0.x * wc[c][0].x + a1.x * wc[c][0].y + a2.x * wc[c][0].z + a3.x * wc[c][0].w + a3.x;
            y[c][1] = a0.y * wc[c][1].x + a1.y * wc[c][1].y + a2.y * wc[c][1].z + a3.y * wc[c][1].w + a3.y;
            y[c][2] = a0.z * wc[c][2].x + a1.z * wc[c][2].y + a2.z * wc[c][2].z + a3.z * wc[c][2].w + a3.z;
            y[c][3] = a0.w * wc[c][3].x + a1.w * wc[c][3].y + a2.w * wc[c][3].z + a3.w * wc[c][3].w + a3.w;
            sum += y[c][0] + y[c][1] + y[c][2] + y[c][3];
            sq  += y[c][0] * y[c][0] + y[c][1] * y[c][1]
                 + y[c][2] * y[c][2] + y[c][3] * y[c][3];
        }

        // ---- per-row block reduction ----
        #pragma unroll
        for (int off = 32; off > 0; off >>= 1) {
            sum += __shfl_down(sum, off, 64);
            sq  += __shfl_down(sq,  off, 64);
        }
        if (lane == 0) { s_sum[r][wave] = sum; s_sq[r][wave] = sq; }
        __syncthreads();   // per-row slots -> no WAR hazard across rows

        float tot = 0.f, totq = 0.f;
        #pragma unroll
        for (int i = 0; i < WAVES; ++i) { tot += s_sum[r][i]; totq += s_sq[r][i]; }

        const float inv_h = 1.0f / (float)H;
        const float mu    = tot * inv_h;
        const float var   = totq * inv_h - mu * mu;
        const float rstd  = rsqrtf(var + EPS);

        // ---- normalize + affine + store ----
        #pragma unroll
        for (int c = 0; c < COLS; ++c) {
            float4 o;
            o.x = (y[c][0] - mu) * rstd * gg[c].x + bb[c].x;
            o.y = (y[c][1] - mu) * rstd * gg[c].y + bb[c].y;
            o.z = (y[c][2] - mu) * rstd * gg[c].z + bb[c].z;
            o.w = (y[c][3] - mu) * rstd * gg[c].w + bb[c].w;
            o4[(rowbase + l0 + r) * H4 + jj[c]] = o;
        }

        // ---- slide the window ----
        #pragma unroll
        for (int c = 0; c < COLS; ++c) {
            xw[c][0] = xw[c][1];
            xw[c][1] = xw[c][2];
            xw[c][2] = xw[c][3];
            if (r + 1 < ROWS) xw[c][3] = xn[c];
        }
    }
}

extern "C" void kernel_launch(void* const* d_in, const int* in_sizes, int n_in,
                              void* d_out, int out_size, void* d_ws, size_t ws_size,
                              hipStream_t stream) {
    const float4* x     = (const float4*)d_in[0];
    const float4* w     = (const float4*)d_in[1];
    const float4* gamma = (const float4*)d_in[2];
    const float4* beta  = (const float4*)d_in[3];
    float4* out = (float4*)d_out;

    dim3 grid(TILES);
    dim3 block(THREADS);
    fused_conv_res_ln<<<grid, block, 0, stream>>>(x, w, gamma, beta, out);
}